// Round 1
// baseline (2621.094 us; speedup 1.0000x reference)
//
#include <hip/hip_runtime.h>
#include <math.h>

// AFNO-3D: rfftn(32^3, ortho) -> blockdiag complex MLP (8 x 96x96, GELU, softshrink) -> irfftn + residual
// B=2, C=768 (8 blocks x 96), H=W=D=32, Dr=17. kept==Dr -> no truncation.

#define CH    768
#define DR    17
#define PLANE 544            // 32*17 (kw,kd) plane elements
#define NVOL  49152          // B*C*H = 2*768*32
#define CSTRIDE 17408        // 32*PLANE, per-channel complex elements
#define ORTHO 0.0055242717280199026f   // 1/sqrt(32768)
#define TWOPI_32 0.19634954084936207f  // 2*pi/32

__device__ __forceinline__ float gelu_f(float v) {
    return 0.5f * v * (1.0f + erff(v * 0.7071067811865475f));
}
__device__ __forceinline__ float sshrink(float v) {
    float a = fabsf(v) - 0.01f;
    return a > 0.f ? copysignf(a, v) : 0.f;
}

// ---------------- K1: forward D (real->17) + W DFT per (b,c,h) plane ----------------
__global__ __launch_bounds__(256) void k1_fwd_dw(const float* __restrict__ x,
                                                 float2* __restrict__ A) {
    __shared__ float  sx[1024];        // [w][d]
    __shared__ float2 s1[32][DR];      // [w][kd]
    __shared__ float2 tw[32];          // e^{-2pi i m/32}
    const int t = threadIdx.x;
    if (t < 32) { float s, c; sincosf(-TWOPI_32 * (float)t, &s, &c); tw[t] = make_float2(c, s); }
    const size_t pb = (size_t)blockIdx.x * 1024;
    for (int i = t; i < 1024; i += 256) sx[i] = x[pb + i];
    __syncthreads();
    // D-axis real DFT: out[w][kd] = sum_d x[w][d] e^{-2pi i d kd/32}
    for (int idx = t; idx < PLANE; idx += 256) {
        int w = idx / DR, kd = idx - w * DR;
        float ar = 0.f, ai = 0.f;
        const float* row = &sx[w * 32];
        #pragma unroll
        for (int d = 0; d < 32; d++) {
            float2 e = tw[(d * kd) & 31];
            float v = row[d];
            ar = fmaf(v, e.x, ar);
            ai = fmaf(v, e.y, ai);
        }
        s1[w][kd] = make_float2(ar, ai);
    }
    __syncthreads();
    // W-axis DFT + ortho scale (full 1/sqrt(32768) folded here)
    const size_t ab = (size_t)blockIdx.x * PLANE;
    for (int idx = t; idx < PLANE; idx += 256) {
        int kw = idx / DR, kd = idx - kw * DR;
        float ar = 0.f, ai = 0.f;
        #pragma unroll
        for (int w = 0; w < 32; w++) {
            float2 e = tw[(w * kw) & 31];
            float2 v = s1[w][kd];
            ar += v.x * e.x - v.y * e.y;
            ai += v.x * e.y + v.y * e.x;
        }
        A[ab + idx] = make_float2(ar * ORTHO, ai * ORTHO);
    }
}

// ---------------- K2: H-axis complex DFT (fwd) / inverse DFT (INV), in-place ----------------
template <bool INV>
__global__ __launch_bounds__(256) void k2_fft_h(float2* __restrict__ A) {
    __shared__ float2 sh[32][32];      // [h][j]
    __shared__ float2 tw[32];
    const int t = threadIdx.x;
    if (t < 32) {
        float s, c; sincosf(-TWOPI_32 * (float)t, &s, &c);
        tw[t] = make_float2(c, INV ? -s : s);  // conj for inverse
    }
    const int p0 = blockIdx.x * 32;            // 17 chunks of 32 over PLANE
    const size_t cb = (size_t)blockIdx.y * CSTRIDE;
    for (int idx = t; idx < 1024; idx += 256) {
        int h = idx >> 5, j = idx & 31;
        sh[h][j] = A[cb + (size_t)h * PLANE + p0 + j];
    }
    __syncthreads();
    for (int idx = t; idx < 1024; idx += 256) {
        int kh = idx >> 5, j = idx & 31;
        float ar = 0.f, ai = 0.f;
        #pragma unroll
        for (int h = 0; h < 32; h++) {
            float2 e = tw[(h * kh) & 31];
            float2 v = sh[h][j];
            ar += v.x * e.x - v.y * e.y;
            ai += v.x * e.y + v.y * e.x;
        }
        A[cb + (size_t)kh * PLANE + p0 + j] = make_float2(ar, ai);
    }
}

// ---------------- K3: per-frequency block-diagonal complex MLP, in-place ----------------
// grid: (17 chunks, 32 h, 16 b*n); tile: 96 channels x 32 positions
__global__ __launch_bounds__(256) void k3_mix(float2* __restrict__ A,
    const float* __restrict__ w1r, const float* __restrict__ w1i,
    const float* __restrict__ w2r, const float* __restrict__ w2i,
    const float* __restrict__ b1r, const float* __restrict__ b1i,
    const float* __restrict__ b2r, const float* __restrict__ b2i) {
    __shared__ float2 sX[96][32];      // 24KB: input tile, later h1 tile, later h2 tile
    __shared__ float  swr[16][96];     // 6KB weight chunk (real)
    __shared__ float  swi[16][96];     // 6KB weight chunk (imag)
    const int t = threadIdx.x;
    const int chunk = blockIdx.x, h = blockIdx.y, bn = blockIdx.z;
    const int b = bn >> 3, n = bn & 7;
    const int p0 = chunk * 32;
    const size_t base = ((size_t)(b * CH + n * 96) * 32 + (size_t)h) * PLANE + p0;

    for (int idx = t; idx < 96 * 32; idx += 256) {
        int i = idx >> 5, j = idx & 31;
        sX[i][j] = A[base + (size_t)i * CSTRIDE + j];
    }
    const int og = t & 31, jg = t >> 5;   // o = og*3+oo (96), j = jg*4+jj (32)
    float2 acc[3][4];

    // ---- layer 1: h1 = X * W1 + b1 ----
    #pragma unroll
    for (int oo = 0; oo < 3; oo++) {
        int o = og * 3 + oo;
        float br = b1r[n * 96 + o], bi = b1i[n * 96 + o];
        #pragma unroll
        for (int jj = 0; jj < 4; jj++) acc[oo][jj] = make_float2(br, bi);
    }
    const float* W1r = w1r + n * 96 * 96;
    const float* W1i = w1i + n * 96 * 96;
    for (int ic = 0; ic < 96; ic += 16) {
        __syncthreads();
        for (int idx = t; idx < 16 * 96; idx += 256) {
            int ii = idx / 96, oo = idx - ii * 96;
            swr[ii][oo] = W1r[(ic + ii) * 96 + oo];
            swi[ii][oo] = W1i[(ic + ii) * 96 + oo];
        }
        __syncthreads();
        for (int ii = 0; ii < 16; ii++) {
            float2 xv[4];
            #pragma unroll
            for (int jj = 0; jj < 4; jj++) xv[jj] = sX[ic + ii][jg * 4 + jj];
            #pragma unroll
            for (int oo = 0; oo < 3; oo++) {
                float wr = swr[ii][og * 3 + oo], wi = swi[ii][og * 3 + oo];
                #pragma unroll
                for (int jj = 0; jj < 4; jj++) {
                    acc[oo][jj].x = fmaf(xv[jj].x, wr, fmaf(-xv[jj].y, wi, acc[oo][jj].x));
                    acc[oo][jj].y = fmaf(xv[jj].x, wi, fmaf( xv[jj].y, wr, acc[oo][jj].y));
                }
            }
        }
    }
    #pragma unroll
    for (int oo = 0; oo < 3; oo++)
        #pragma unroll
        for (int jj = 0; jj < 4; jj++) {
            acc[oo][jj].x = gelu_f(acc[oo][jj].x);
            acc[oo][jj].y = gelu_f(acc[oo][jj].y);
        }
    __syncthreads();   // all reads of X done
    #pragma unroll
    for (int oo = 0; oo < 3; oo++)
        #pragma unroll
        for (int jj = 0; jj < 4; jj++)
            sX[og * 3 + oo][jg * 4 + jj] = acc[oo][jj];

    // ---- layer 2: h2 = h1 * W2 + b2 ----
    #pragma unroll
    for (int oo = 0; oo < 3; oo++) {
        int o = og * 3 + oo;
        float br = b2r[n * 96 + o], bi = b2i[n * 96 + o];
        #pragma unroll
        for (int jj = 0; jj < 4; jj++) acc[oo][jj] = make_float2(br, bi);
    }
    const float* W2r = w2r + n * 96 * 96;
    const float* W2i = w2i + n * 96 * 96;
    for (int ic = 0; ic < 96; ic += 16) {
        __syncthreads();   // h1 writes visible; prev weight-chunk reads done
        for (int idx = t; idx < 16 * 96; idx += 256) {
            int ii = idx / 96, oo = idx - ii * 96;
            swr[ii][oo] = W2r[(ic + ii) * 96 + oo];
            swi[ii][oo] = W2i[(ic + ii) * 96 + oo];
        }
        __syncthreads();
        for (int ii = 0; ii < 16; ii++) {
            float2 xv[4];
            #pragma unroll
            for (int jj = 0; jj < 4; jj++) xv[jj] = sX[ic + ii][jg * 4 + jj];
            #pragma unroll
            for (int oo = 0; oo < 3; oo++) {
                float wr = swr[ii][og * 3 + oo], wi = swi[ii][og * 3 + oo];
                #pragma unroll
                for (int jj = 0; jj < 4; jj++) {
                    acc[oo][jj].x = fmaf(xv[jj].x, wr, fmaf(-xv[jj].y, wi, acc[oo][jj].x));
                    acc[oo][jj].y = fmaf(xv[jj].x, wi, fmaf( xv[jj].y, wr, acc[oo][jj].y));
                }
            }
        }
    }
    // softshrink, then coalesced in-place write-back via LDS transpose
    #pragma unroll
    for (int oo = 0; oo < 3; oo++)
        #pragma unroll
        for (int jj = 0; jj < 4; jj++) {
            acc[oo][jj].x = sshrink(acc[oo][jj].x);
            acc[oo][jj].y = sshrink(acc[oo][jj].y);
        }
    __syncthreads();   // all h1 reads done
    #pragma unroll
    for (int oo = 0; oo < 3; oo++)
        #pragma unroll
        for (int jj = 0; jj < 4; jj++)
            sX[og * 3 + oo][jg * 4 + jj] = acc[oo][jj];
    __syncthreads();
    for (int idx = t; idx < 96 * 32; idx += 256) {
        int i = idx >> 5, j = idx & 31;
        A[base + (size_t)i * CSTRIDE + j] = sX[i][j];
    }
}

// ---------------- K5: inverse W DFT + inverse real D DFT + residual ----------------
__global__ __launch_bounds__(256) void k5_inv_wd(const float2* __restrict__ A,
                                                 const float* __restrict__ x,
                                                 float* __restrict__ out) {
    __shared__ float2 sz[PLANE];       // [kw][kd]
    __shared__ float2 sg[32][DR];      // [w][kd]
    __shared__ float2 tw[32];          // e^{+2pi i m/32}
    const int t = threadIdx.x;
    if (t < 32) { float s, c; sincosf(TWOPI_32 * (float)t, &s, &c); tw[t] = make_float2(c, s); }
    const size_t ab = (size_t)blockIdx.x * PLANE;
    for (int idx = t; idx < PLANE; idx += 256) sz[idx] = A[ab + idx];
    __syncthreads();
    // inverse W: G[w][kd] = sum_kw Z[kw][kd] e^{+2pi i w kw/32}
    for (int idx = t; idx < PLANE; idx += 256) {
        int w = idx / DR, kd = idx - w * DR;
        float ar = 0.f, ai = 0.f;
        #pragma unroll
        for (int kw = 0; kw < 32; kw++) {
            float2 e = tw[(w * kw) & 31];
            float2 v = sz[kw * DR + kd];
            ar += v.x * e.x - v.y * e.y;
            ai += v.x * e.y + v.y * e.x;
        }
        sg[w][kd] = make_float2(ar, ai);
    }
    __syncthreads();
    // inverse real D (c2r semantics: Im of DC/Nyquist bins ignored) + ortho scale + residual
    const size_t pb = (size_t)blockIdx.x * 1024;
    for (int idx = t; idx < 1024; idx += 256) {
        int w = idx >> 5, d = idx & 31;
        float v = sg[w][0].x + ((d & 1) ? -sg[w][16].x : sg[w][16].x);
        float s2 = 0.f;
        #pragma unroll
        for (int kd = 1; kd < 16; kd++) {
            float2 e = tw[(d * kd) & 31];
            float2 g = sg[w][kd];
            s2 += g.x * e.x - g.y * e.y;   // Re(g * e^{+i theta})
        }
        v += 2.f * s2;
        out[pb + idx] = v * ORTHO + x[pb + idx];
    }
}

extern "C" void kernel_launch(void* const* d_in, const int* in_sizes, int n_in,
                              void* d_out, int out_size, void* d_ws, size_t ws_size,
                              hipStream_t stream) {
    const float* x   = (const float*)d_in[0];
    const float* w1r = (const float*)d_in[1];
    const float* w1i = (const float*)d_in[2];
    const float* w2r = (const float*)d_in[3];
    const float* w2i = (const float*)d_in[4];
    const float* b1r = (const float*)d_in[5];
    const float* b1i = (const float*)d_in[6];
    const float* b2r = (const float*)d_in[7];
    const float* b2i = (const float*)d_in[8];
    float* out = (float*)d_out;
    float2* A = (float2*)d_ws;   // 49152*544*8 = 214 MB spectrum buffer

    k1_fwd_dw<<<NVOL, 256, 0, stream>>>(x, A);
    k2_fft_h<false><<<dim3(17, 1536), 256, 0, stream>>>(A);
    k3_mix<<<dim3(17, 32, 16), 256, 0, stream>>>(A, w1r, w1i, w2r, w2i, b1r, b1i, b2r, b2i);
    k2_fft_h<true><<<dim3(17, 1536), 256, 0, stream>>>(A);
    k5_inv_wd<<<NVOL, 256, 0, stream>>>(A, x, out);
}

// Round 2
// 1298.251 us; speedup vs baseline: 2.0189x; 2.0189x over previous
//
#include <hip/hip_runtime.h>
#include <math.h>

// AFNO-3D: rfftn(32^3, ortho) -> blockdiag complex MLP (8 x 96x96, GELU, softshrink) -> irfftn + residual
// B=2, C=768 (8 blocks x 96), H=W=D=32, Dr=17. kept==Dr -> no truncation.

#define CH    768
#define DR    17
#define PLANE 544            // 32*17 (kw,kd) plane elements
#define NVOL  49152          // B*C*H = 2*768*32
#define CSTRIDE 17408        // 32*PLANE, per-channel complex elements
#define ORTHO 0.0055242717280199026f   // 1/sqrt(32768)
#define TWOPI_32 0.19634954084936207f  // 2*pi/32

typedef __bf16 bf16x8 __attribute__((ext_vector_type(8)));
typedef float  f32x4  __attribute__((ext_vector_type(4)));

__device__ __forceinline__ float gelu_f(float v) {
    return 0.5f * v * (1.0f + erff(v * 0.7071067811865475f));
}
__device__ __forceinline__ float sshrink(float v) {
    float a = fabsf(v) - 0.01f;
    return a > 0.f ? copysignf(a, v) : 0.f;
}
__device__ __forceinline__ bf16x8 ld8(const __bf16* p) { return *(const bf16x8*)p; }

// ---------------- K1: forward D (real->17) + W DFT per (b,c,h) plane (fp32 scalar) ----------------
__global__ __launch_bounds__(256) void k1_fwd_dw(const float* __restrict__ x,
                                                 float2* __restrict__ A) {
    __shared__ float  sx[1024];        // [w][d]
    __shared__ float2 s1[32][DR];      // [w][kd]
    __shared__ float2 tw[32];          // e^{-2pi i m/32}
    const int t = threadIdx.x;
    if (t < 32) { float s, c; sincosf(-TWOPI_32 * (float)t, &s, &c); tw[t] = make_float2(c, s); }
    const size_t pb = (size_t)blockIdx.x * 1024;
    for (int i = t; i < 1024; i += 256) sx[i] = x[pb + i];
    __syncthreads();
    for (int idx = t; idx < PLANE; idx += 256) {
        int w = idx / DR, kd = idx - w * DR;
        float ar = 0.f, ai = 0.f;
        const float* row = &sx[w * 32];
        #pragma unroll
        for (int d = 0; d < 32; d++) {
            float2 e = tw[(d * kd) & 31];
            float v = row[d];
            ar = fmaf(v, e.x, ar);
            ai = fmaf(v, e.y, ai);
        }
        s1[w][kd] = make_float2(ar, ai);
    }
    __syncthreads();
    const size_t ab = (size_t)blockIdx.x * PLANE;
    for (int idx = t; idx < PLANE; idx += 256) {
        int kw = idx / DR, kd = idx - kw * DR;
        float ar = 0.f, ai = 0.f;
        #pragma unroll
        for (int w = 0; w < 32; w++) {
            float2 e = tw[(w * kw) & 31];
            float2 v = s1[w][kd];
            ar += v.x * e.x - v.y * e.y;
            ai += v.x * e.y + v.y * e.x;
        }
        A[ab + idx] = make_float2(ar * ORTHO, ai * ORTHO);
    }
}

// ---------------- K2: H-axis complex DFT via bf16 MFMA, in-place ----------------
// Per (b,c): Y = E(32x32) * X(32x544). Grid (2 chunks of 272 positions, 1536 channels).
template <bool INV>
__global__ __launch_bounds__(256) void k2_fft_h(float2* __restrict__ A) {
    __shared__ float2 twf[32];
    __shared__ __align__(16) __bf16 sEr[32][40],  sEi[32][40];   // A-operand [kh][h]
    __shared__ __align__(16) __bf16 sBr[272][40], sBi[272][40];  // B^T operand [p][h]
    const int t = threadIdx.x;
    if (t < 32) {
        float s, c; sincosf(-TWOPI_32 * (float)t, &s, &c);
        twf[t] = make_float2(c, INV ? -s : s);
    }
    __syncthreads();
    for (int idx = t; idx < 1024; idx += 256) {
        int kh = idx >> 5, h = idx & 31;
        float2 e = twf[(kh * h) & 31];
        sEr[kh][h] = (__bf16)e.x;
        sEi[kh][h] = (__bf16)e.y;
    }
    const int p0g = blockIdx.x * 272;
    const size_t cb = (size_t)blockIdx.y * CSTRIDE;
    for (int idx = t; idx < 8704; idx += 256) {
        int h = idx / 272, p = idx - h * 272;
        float2 v = A[cb + (size_t)h * PLANE + p0g + p];
        sBr[p][h] = (__bf16)v.x;
        sBi[p][h] = (__bf16)v.y;
    }
    __syncthreads();
    const int wave = t >> 6, lane = t & 63, row = lane & 15, quad = lane >> 4;
    for (int j = wave; j < 34; j += 4) {     // 2 M-tiles x 17 N-tiles
        int mt = j & 1, nt = j >> 1;
        int m0 = mt * 16, n0 = nt * 16;
        bf16x8 ar = ld8(&sEr[m0 + row][quad * 8]);
        bf16x8 ai = ld8(&sEi[m0 + row][quad * 8]);
        bf16x8 br = ld8(&sBr[n0 + row][quad * 8]);
        bf16x8 bi = ld8(&sBi[n0 + row][quad * 8]);
        f32x4 rp = {0.f,0.f,0.f,0.f}, rm = {0.f,0.f,0.f,0.f}, im = {0.f,0.f,0.f,0.f};
        rp = __builtin_amdgcn_mfma_f32_16x16x32_bf16(ar, br, rp, 0, 0, 0);
        rm = __builtin_amdgcn_mfma_f32_16x16x32_bf16(ai, bi, rm, 0, 0, 0);
        im = __builtin_amdgcn_mfma_f32_16x16x32_bf16(ar, bi, im, 0, 0, 0);
        im = __builtin_amdgcn_mfma_f32_16x16x32_bf16(ai, br, im, 0, 0, 0);
        int p = p0g + n0 + row;
        #pragma unroll
        for (int r = 0; r < 4; r++) {
            int kh = m0 + quad * 4 + r;
            A[cb + (size_t)kh * PLANE + p] = make_float2(rp[r] - rm[r], im[r]);
        }
    }
}

// ---------------- K3: block-diagonal complex MLP via bf16 MFMA, in-place ----------------
// Per (b,n): complex GEMM [96x96]*[96x17408]; grid (272 chunks of 64 positions, 16 b*n).
__global__ __launch_bounds__(256) void k3_mix(float2* __restrict__ A,
    const float* __restrict__ w1r, const float* __restrict__ w1i,
    const float* __restrict__ w2r, const float* __restrict__ w2i,
    const float* __restrict__ b1r, const float* __restrict__ b1i,
    const float* __restrict__ b2r, const float* __restrict__ b2i) {
    __shared__ __align__(16) __bf16 sWr[96][104], sWi[96][104];  // A-operand: [o][i] = W^T
    __shared__ __align__(16) __bf16 sXr[64][104], sXi[64][104];  // B^T operand: [p][i]
    const int t = threadIdx.x;
    const int chunk = blockIdx.x, bn = blockIdx.y;
    const int b = bn >> 3, n = bn & 7;
    const size_t base = (size_t)(b * CH + n * 96) * CSTRIDE + chunk * 64;

    // stage W1^T (bf16) — global reads coalesced over o, LDS write transposed
    const float* W1r = w1r + n * 9216;
    const float* W1i = w1i + n * 9216;
    for (int idx = t; idx < 9216; idx += 256) {
        int i = idx / 96, o = idx - i * 96;
        sWr[o][i] = (__bf16)W1r[idx];
        sWi[o][i] = (__bf16)W1i[idx];
    }
    // stage X^T: [p][i]
    for (int idx = t; idx < 6144; idx += 256) {
        int i = idx >> 6, p = idx & 63;
        float2 v = A[base + (size_t)i * CSTRIDE + p];
        sXr[p][i] = (__bf16)v.x;
        sXi[p][i] = (__bf16)v.y;
    }
    __syncthreads();

    const int wave = t >> 6, lane = t & 63, row = lane & 15, quad = lane >> 4;
    float h1s[6][8];

    // ---- layer 1: 6 M-tiles x 4 N-tiles = 24 jobs, 6 per wave ----
    #pragma unroll
    for (int q = 0; q < 6; q++) {
        int job = wave * 6 + q, mt = job >> 2, nt = job & 3;
        int m0 = mt * 16, p0 = nt * 16;
        f32x4 rp = {0.f,0.f,0.f,0.f}, rm = {0.f,0.f,0.f,0.f}, im = {0.f,0.f,0.f,0.f};
        #pragma unroll
        for (int ks = 0; ks < 3; ks++) {
            int k0 = ks * 32 + quad * 8;
            bf16x8 ar = ld8(&sWr[m0 + row][k0]);
            bf16x8 ai = ld8(&sWi[m0 + row][k0]);
            bf16x8 br = ld8(&sXr[p0 + row][k0]);
            bf16x8 bi = ld8(&sXi[p0 + row][k0]);
            rp = __builtin_amdgcn_mfma_f32_16x16x32_bf16(ar, br, rp, 0, 0, 0);
            rm = __builtin_amdgcn_mfma_f32_16x16x32_bf16(ai, bi, rm, 0, 0, 0);
            im = __builtin_amdgcn_mfma_f32_16x16x32_bf16(ar, bi, im, 0, 0, 0);
            im = __builtin_amdgcn_mfma_f32_16x16x32_bf16(ai, br, im, 0, 0, 0);
        }
        #pragma unroll
        for (int r = 0; r < 4; r++) {
            int o = m0 + quad * 4 + r;
            float hr = b1r[n * 96 + o] + rp[r] - rm[r];
            float hi = b1i[n * 96 + o] + im[r];
            h1s[q][r]     = gelu_f(hr);
            h1s[q][4 + r] = gelu_f(hi);
        }
    }
    __syncthreads();   // all waves done reading sW (W1) and sX (X)

    // write h1 into sX (B^T layout [p][o]) and stage W2^T into sW
    #pragma unroll
    for (int q = 0; q < 6; q++) {
        int job = wave * 6 + q, mt = job >> 2, nt = job & 3;
        int m0 = mt * 16, p0 = nt * 16;
        int p = p0 + row;
        #pragma unroll
        for (int r = 0; r < 4; r++) {
            int o = m0 + quad * 4 + r;
            sXr[p][o] = (__bf16)h1s[q][r];
            sXi[p][o] = (__bf16)h1s[q][4 + r];
        }
    }
    const float* W2r = w2r + n * 9216;
    const float* W2i = w2i + n * 9216;
    for (int idx = t; idx < 9216; idx += 256) {
        int i = idx / 96, o = idx - i * 96;
        sWr[o][i] = (__bf16)W2r[idx];
        sWi[o][i] = (__bf16)W2i[idx];
    }
    __syncthreads();

    // ---- layer 2 + softshrink + coalesced global write ----
    #pragma unroll
    for (int q = 0; q < 6; q++) {
        int job = wave * 6 + q, mt = job >> 2, nt = job & 3;
        int m0 = mt * 16, p0 = nt * 16;
        f32x4 rp = {0.f,0.f,0.f,0.f}, rm = {0.f,0.f,0.f,0.f}, im = {0.f,0.f,0.f,0.f};
        #pragma unroll
        for (int ks = 0; ks < 3; ks++) {
            int k0 = ks * 32 + quad * 8;
            bf16x8 ar = ld8(&sWr[m0 + row][k0]);
            bf16x8 ai = ld8(&sWi[m0 + row][k0]);
            bf16x8 br = ld8(&sXr[p0 + row][k0]);
            bf16x8 bi = ld8(&sXi[p0 + row][k0]);
            rp = __builtin_amdgcn_mfma_f32_16x16x32_bf16(ar, br, rp, 0, 0, 0);
            rm = __builtin_amdgcn_mfma_f32_16x16x32_bf16(ai, bi, rm, 0, 0, 0);
            im = __builtin_amdgcn_mfma_f32_16x16x32_bf16(ar, bi, im, 0, 0, 0);
            im = __builtin_amdgcn_mfma_f32_16x16x32_bf16(ai, br, im, 0, 0, 0);
        }
        int p = p0 + row;
        #pragma unroll
        for (int r = 0; r < 4; r++) {
            int o = m0 + quad * 4 + r;
            float hr = sshrink(b2r[n * 96 + o] + rp[r] - rm[r]);
            float hi = sshrink(b2i[n * 96 + o] + im[r]);
            A[base + (size_t)o * CSTRIDE + p] = make_float2(hr, hi);
        }
    }
}

// ---------------- K5: inverse W DFT + inverse real D DFT + residual (fp32 scalar) ----------------
__global__ __launch_bounds__(256) void k5_inv_wd(const float2* __restrict__ A,
                                                 const float* __restrict__ x,
                                                 float* __restrict__ out) {
    __shared__ float2 sz[PLANE];       // [kw][kd]
    __shared__ float2 sg[32][DR];      // [w][kd]
    __shared__ float2 tw[32];          // e^{+2pi i m/32}
    const int t = threadIdx.x;
    if (t < 32) { float s, c; sincosf(TWOPI_32 * (float)t, &s, &c); tw[t] = make_float2(c, s); }
    const size_t ab = (size_t)blockIdx.x * PLANE;
    for (int idx = t; idx < PLANE; idx += 256) sz[idx] = A[ab + idx];
    __syncthreads();
    for (int idx = t; idx < PLANE; idx += 256) {
        int w = idx / DR, kd = idx - w * DR;
        float ar = 0.f, ai = 0.f;
        #pragma unroll
        for (int kw = 0; kw < 32; kw++) {
            float2 e = tw[(w * kw) & 31];
            float2 v = sz[kw * DR + kd];
            ar += v.x * e.x - v.y * e.y;
            ai += v.x * e.y + v.y * e.x;
        }
        sg[w][kd] = make_float2(ar, ai);
    }
    __syncthreads();
    const size_t pb = (size_t)blockIdx.x * 1024;
    for (int idx = t; idx < 1024; idx += 256) {
        int w = idx >> 5, d = idx & 31;
        float v = sg[w][0].x + ((d & 1) ? -sg[w][16].x : sg[w][16].x);
        float s2 = 0.f;
        #pragma unroll
        for (int kd = 1; kd < 16; kd++) {
            float2 e = tw[(d * kd) & 31];
            float2 g = sg[w][kd];
            s2 += g.x * e.x - g.y * e.y;
        }
        v += 2.f * s2;
        out[pb + idx] = v * ORTHO + x[pb + idx];
    }
}

extern "C" void kernel_launch(void* const* d_in, const int* in_sizes, int n_in,
                              void* d_out, int out_size, void* d_ws, size_t ws_size,
                              hipStream_t stream) {
    const float* x   = (const float*)d_in[0];
    const float* w1r = (const float*)d_in[1];
    const float* w1i = (const float*)d_in[2];
    const float* w2r = (const float*)d_in[3];
    const float* w2i = (const float*)d_in[4];
    const float* b1r = (const float*)d_in[5];
    const float* b1i = (const float*)d_in[6];
    const float* b2r = (const float*)d_in[7];
    const float* b2i = (const float*)d_in[8];
    float* out = (float*)d_out;
    float2* A = (float2*)d_ws;   // 49152*544*8 = 214 MB spectrum buffer

    k1_fwd_dw<<<NVOL, 256, 0, stream>>>(x, A);
    k2_fft_h<false><<<dim3(2, 1536), 256, 0, stream>>>(A);
    k3_mix<<<dim3(272, 16), 256, 0, stream>>>(A, w1r, w1i, w2r, w2i, b1r, b1i, b2r, b2i);
    k2_fft_h<true><<<dim3(2, 1536), 256, 0, stream>>>(A);
    k5_inv_wd<<<NVOL, 256, 0, stream>>>(A, x, out);
}